// Round 1
// baseline (2433.774 us; speedup 1.0000x reference)
//
#include <hip/hip_runtime.h>

#define NN 38332
#define NE 1200000
#define CC 64
#define POI 38333

__device__ __forceinline__ float lrelu01(float v){ return v > 0.f ? v : 0.01f*v; }

// ---------------- setup: degrees + CSR ----------------
__global__ __launch_bounds__(256) void k_init(float* wdeg, int* counts){
  int i = blockIdx.x*256 + threadIdx.x;
  if (i < NN){ wdeg[i] = 1.0f; counts[i] = 0; }
}

__global__ __launch_bounds__(256) void k_hist(const int* __restrict__ dst,
                                              const float* __restrict__ w,
                                              float* wdeg, int* counts){
  int e = blockIdx.x*256 + threadIdx.x;
  if (e < NE){
    int d = dst[e];
    atomicAdd(&counts[d], 1);
    atomicAdd(&wdeg[d], w[e]);
  }
}

__global__ __launch_bounds__(256) void k_dinv(const float* __restrict__ wdeg, float* dinv){
  int i = blockIdx.x*256 + threadIdx.x;
  if (i < NN) dinv[i] = rsqrtf(wdeg[i]);   // deg >= 1 always (self loop)
}

__global__ __launch_bounds__(1024) void k_scan(const int* __restrict__ counts,
                                               int* rowptr, int* cursor){
  __shared__ int part[1024];
  int tid = threadIdx.x;
  const int per = (NN + 1023)/1024;
  int base = tid*per;
  int s = 0;
  for (int k = 0; k < per; k++){ int i = base + k; if (i < NN) s += counts[i]; }
  part[tid] = s;
  __syncthreads();
  for (int off = 1; off < 1024; off <<= 1){
    int v = (tid >= off) ? part[tid-off] : 0;
    __syncthreads();
    part[tid] += v;
    __syncthreads();
  }
  int run = (tid == 0) ? 0 : part[tid-1];
  for (int k = 0; k < per; k++){
    int i = base + k;
    if (i < NN){ rowptr[i] = run; cursor[i] = run; run += counts[i]; }
  }
  if (tid == 1023) rowptr[NN] = run;   // == NE
}

__global__ __launch_bounds__(256) void k_csr(const int* __restrict__ src,
                                             const int* __restrict__ dst,
                                             const float* __restrict__ ew,
                                             const float* __restrict__ dinv,
                                             int* cursor, int* __restrict__ col,
                                             float* __restrict__ nrm){
  int e = blockIdx.x*256 + threadIdx.x;
  if (e < NE){
    int s = src[e], d = dst[e];
    int p = atomicAdd(&cursor[d], 1);
    col[p] = s;
    nrm[p] = dinv[s]*ew[e]*dinv[d];
  }
}

// ---------------- input linear: concat(poi,cat,feat) @ W_in ----------------
__global__ __launch_bounds__(256) void k_in_linear(const int* __restrict__ poi_idx,
                                                   const int* __restrict__ cat_idx,
                                                   const float* __restrict__ feat,
                                                   const float* __restrict__ poi_emb,
                                                   const float* __restrict__ cat_emb,
                                                   const float* __restrict__ W,
                                                   float* __restrict__ h){
  __shared__ float row[4][404];
  int lane = threadIdx.x & 63, wave = threadIdx.x >> 6;
  int n = blockIdx.x*4 + wave;           // grid is exact: NN % 4 == 0
  int pi = poi_idx[n], ci = cat_idx[n];
  for (int k = lane; k < 403; k += 64){
    float v;
    if (k < 300)      v = poi_emb[pi*300 + k];
    else if (k < 400) v = cat_emb[ci*100 + (k-300)];
    else              v = feat[n*3 + (k-400)];
    row[wave][k] = v;
  }
  __syncthreads();
  float acc = 0.f;
  for (int k = 0; k < 403; k++) acc = fmaf(row[wave][k], W[k*64 + lane], acc);
  h[(size_t)n*64 + lane] = acc;
}

// ---------------- 64x64 linear ----------------
__global__ __launch_bounds__(256) void k_linear64(const float* __restrict__ x,
                                                  const float* __restrict__ W,
                                                  float* __restrict__ h){
  __shared__ float Ws[4096];
  int tid = threadIdx.x;
  for (int i = tid; i < 4096; i += 256) Ws[i] = W[i];
  __syncthreads();
  int lane = tid & 63, wave = tid >> 6;
  for (int j = 0; j < 8; j++){
    int n = blockIdx.x*32 + wave*8 + j;
    if (n < NN){
      float xv = x[(size_t)n*64 + lane];
      float acc = 0.f;
      #pragma unroll
      for (int k = 0; k < 64; k++) acc = fmaf(__shfl(xv, k), Ws[k*64 + lane], acc);
      h[(size_t)n*64 + lane] = acc;
    }
  }
}

// ---------------- GCN propagation (wave per node, lane = channel) ----------------
template<bool DO_LRELU>
__global__ __launch_bounds__(256) void k_gcn_prop(const float* __restrict__ h,
                                                  const int* __restrict__ rowptr,
                                                  const int* __restrict__ col,
                                                  const float* __restrict__ nrm,
                                                  const float* __restrict__ dinv,
                                                  const float* __restrict__ b,
                                                  float* __restrict__ out){
  int lane = threadIdx.x & 63, wave = threadIdx.x >> 6;
  int n = blockIdx.x*4 + wave;
  if (n >= NN) return;
  int beg = rowptr[n], end = rowptr[n+1];
  float di = dinv[n];
  float acc = di*di*h[(size_t)n*64 + lane];
  for (int e = beg; e < end; e++){
    int s = col[e];
    acc = fmaf(nrm[e], h[(size_t)s*64 + lane], acc);
  }
  acc += b[lane];
  if (DO_LRELU) acc = lrelu01(acc);
  out[(size_t)n*64 + lane] = acc;
}

// ---------------- GAT ----------------
__global__ __launch_bounds__(256) void k_att(const float* __restrict__ h,
                                             const float* __restrict__ att_src,
                                             const float* __restrict__ att_dst,
                                             float* __restrict__ a_s, float* __restrict__ a_d){
  int lane = threadIdx.x & 63, wave = threadIdx.x >> 6;
  int n = blockIdx.x*4 + wave;
  if (n >= NN) return;
  float hv = h[(size_t)n*64 + lane];
  float s1 = hv*att_src[lane], s2 = hv*att_dst[lane];
  #pragma unroll
  for (int off = 32; off; off >>= 1){ s1 += __shfl_xor(s1, off); s2 += __shfl_xor(s2, off); }
  if (lane == 0){ a_s[n] = s1; a_d[n] = s2; }
}

__global__ __launch_bounds__(256) void k_gat_prop(const float* __restrict__ h,
                                                  const int* __restrict__ rowptr,
                                                  const int* __restrict__ col,
                                                  const float* __restrict__ a_s,
                                                  const float* __restrict__ a_d,
                                                  const float* __restrict__ b,
                                                  float* __restrict__ out){
  int lane = threadIdx.x & 63, wave = threadIdx.x >> 6;
  int n = blockIdx.x*4 + wave;
  if (n >= NN) return;
  int beg = rowptr[n], end = rowptr[n+1];
  float ad = a_d[n];
  float se = a_s[n] + ad; se = se > 0.f ? se : 0.2f*se;   // self edge
  // phase A: lanes over edges -> max, then exp-sum
  float m = se;
  for (int e = beg + lane; e < end; e += 64){
    float v = a_s[col[e]] + ad; v = v > 0.f ? v : 0.2f*v;
    m = fmaxf(m, v);
  }
  #pragma unroll
  for (int off = 32; off; off >>= 1) m = fmaxf(m, __shfl_xor(m, off));
  float z = 0.f;
  for (int e = beg + lane; e < end; e += 64){
    float v = a_s[col[e]] + ad; v = v > 0.f ? v : 0.2f*v;
    z += __expf(v - m);
  }
  #pragma unroll
  for (int off = 32; off; off >>= 1) z += __shfl_xor(z, off);
  z += __expf(se - m);
  float zinv = 1.0f/(z + 1e-16f);
  // phase B: lanes over channels
  float acc = __expf(se - m)*zinv*h[(size_t)n*64 + lane];
  for (int e = beg; e < end; e++){
    int s = col[e];
    float v = a_s[s] + ad; v = v > 0.f ? v : 0.2f*v;
    float w = __expf(v - m)*zinv;
    acc = fmaf(w, h[(size_t)s*64 + lane], acc);
  }
  out[(size_t)n*64 + lane] = acc + b[lane];
}

// ---------------- GraphNorm ----------------
__global__ __launch_bounds__(128) void k_zero_stats(float* stats){
  if (threadIdx.x < 128) stats[threadIdx.x] = 0.f;
}

__global__ __launch_bounds__(256) void k_colstats(const float* __restrict__ t, float* stats){
  int lane = threadIdx.x & 63;
  int sub  = threadIdx.x >> 6;
  float s = 0.f, s2 = 0.f;
  for (int n = blockIdx.x*4 + sub; n < NN; n += gridDim.x*4){
    float v = t[(size_t)n*64 + lane];
    s += v; s2 = fmaf(v, v, s2);
  }
  __shared__ float ls[256], ls2[256];
  ls[threadIdx.x] = s; ls2[threadIdx.x] = s2;
  __syncthreads();
  if (threadIdx.x < 64){
    s  = ls[threadIdx.x]  + ls[threadIdx.x+64]  + ls[threadIdx.x+128]  + ls[threadIdx.x+192];
    s2 = ls2[threadIdx.x] + ls2[threadIdx.x+64] + ls2[threadIdx.x+128] + ls2[threadIdx.x+192];
    atomicAdd(&stats[threadIdx.x], s);
    atomicAdd(&stats[64 + threadIdx.x], s2);
  }
}

__global__ __launch_bounds__(64) void k_chan(const float* __restrict__ gw,
                                             const float* __restrict__ ga,
                                             float* stats){
  int c = threadIdx.x;
  const float invN = 1.0f/(float)NN;
  float m  = stats[c]*invN;
  float ms = stats[64 + c]*invN;
  float a  = ga[c];
  float var = ms - m*m*a*(2.0f - a);     // mean((x - a*m)^2)
  stats[128 + c] = rsqrtf(var + 1e-5f)*gw[c];  // coef
  stats[192 + c] = a*m;                        // shift
}

__global__ __launch_bounds__(256) void k_resid(const float* __restrict__ t,
                                               const float* __restrict__ stats,
                                               const float* __restrict__ gb,
                                               float* __restrict__ x){
  int i = blockIdx.x*256 + threadIdx.x;
  if (i < NN*64){
    int c = i & 63;
    float v = (t[i] - stats[192 + c])*stats[128 + c] + gb[c];
    x[i] += lrelu01(v);
  }
}

// ---------------- output head ----------------
__global__ __launch_bounds__(256) void k_outlin(const float* __restrict__ x,
                                                const float* __restrict__ Wout,
                                                float* __restrict__ h1){
  int lane = threadIdx.x & 63, wave = threadIdx.x >> 6;
  int n = blockIdx.x*4 + wave;
  if (n >= NN) return;
  float v = x[(size_t)n*64 + lane]*Wout[lane];
  #pragma unroll
  for (int off = 32; off; off >>= 1) v += __shfl_xor(v, off);
  if (lane == 0) h1[n] = v;
}

__global__ __launch_bounds__(256) void k_prop1(const float* __restrict__ h1,
                                               const int* __restrict__ rowptr,
                                               const int* __restrict__ col,
                                               const float* __restrict__ nrm,
                                               const float* __restrict__ dinv,
                                               const float* __restrict__ b_out,
                                               float* __restrict__ xs){
  int n = blockIdx.x*256 + threadIdx.x;
  if (n >= NN) return;
  float di = dinv[n];
  float acc = di*di*h1[n];
  int beg = rowptr[n], end = rowptr[n+1];
  for (int e = beg; e < end; e++) acc = fmaf(nrm[e], h1[col[e]], acc);
  acc += b_out[0];
  xs[n] = lrelu01(acc);
}

__global__ __launch_bounds__(128) void k_fc1_init(const float* __restrict__ fc1_b, float* hfc){
  if (threadIdx.x < 128) hfc[threadIdx.x] = fc1_b[threadIdx.x];
}

__global__ __launch_bounds__(256) void k_fc1(const float* __restrict__ xs,
                                             const float* __restrict__ W,
                                             float* hfc){
  int j = threadIdx.x & 127, half = threadIdx.x >> 7;
  float acc = 0.f;
  for (int n = blockIdx.x*2 + half; n < NN; n += gridDim.x*2)
    acc = fmaf(xs[n], W[(size_t)n*128 + j], acc);
  __shared__ float ls[256];
  ls[threadIdx.x] = acc;
  __syncthreads();
  if (threadIdx.x < 128) atomicAdd(&hfc[j], ls[j] + ls[128 + j]);
}

__global__ __launch_bounds__(256) void k_fc2(const float* __restrict__ hfc,
                                             const float* __restrict__ W2,
                                             const float* __restrict__ b2,
                                             float* __restrict__ out){
  __shared__ float hs[128];
  if (threadIdx.x < 128){ float v = hfc[threadIdx.x]; hs[threadIdx.x] = v > 0.f ? v : 0.f; }
  __syncthreads();
  int p = blockIdx.x*256 + threadIdx.x;
  if (p < POI){
    float acc = b2[p];
    #pragma unroll
    for (int j = 0; j < 128; j++) acc = fmaf(hs[j], W2[(size_t)j*POI + p], acc);
    out[p] = acc > 0.f ? acc : 0.f;
  }
}

// ---------------- launch ----------------
extern "C" void kernel_launch(void* const* d_in, const int* in_sizes, int n_in,
                              void* d_out, int out_size, void* d_ws, size_t ws_size,
                              hipStream_t stream) {
  const int*   poi_idx = (const int*)d_in[0];
  const int*   cat_idx = (const int*)d_in[1];
  const float* feat    = (const float*)d_in[2];
  const int*   eidx    = (const int*)d_in[3];
  const int*   src     = eidx;
  const int*   dst     = eidx + NE;
  const float* ew      = (const float*)d_in[4];
  const float* poi_emb = (const float*)d_in[5];
  const float* cat_emb = (const float*)d_in[6];
  const float* W_in    = (const float*)d_in[7];
  const float* b_in    = (const float*)d_in[8];
  const float* gcn_W   = (const float*)d_in[9];
  const float* gcn_b   = (const float*)d_in[10];
  const float* gn_w    = (const float*)d_in[11];
  const float* gn_b    = (const float*)d_in[12];
  const float* gn_a    = (const float*)d_in[13];
  const float* gat_W   = (const float*)d_in[14];
  const float* att_s   = (const float*)d_in[15];
  const float* att_d   = (const float*)d_in[16];
  const float* gat_b   = (const float*)d_in[17];
  const float* W_out   = (const float*)d_in[18];
  const float* b_out   = (const float*)d_in[19];
  const float* fc1_W   = (const float*)d_in[20];
  const float* fc1_b   = (const float*)d_in[21];
  const float* fc2_W   = (const float*)d_in[22];
  const float* fc2_b   = (const float*)d_in[23];
  float* out = (float*)d_out;

  char* p = (char*)d_ws;
  auto alloc = [&](size_t bytes){ void* r = (void*)p; p += (bytes + 255) & ~(size_t)255; return r; };
  float* x      = (float*)alloc((size_t)NN*64*4);
  float* t      = (float*)alloc((size_t)NN*64*4);
  float* h      = (float*)alloc((size_t)NN*64*4);
  float* dinv   = (float*)alloc(NN*4);
  float* wdeg   = (float*)alloc(NN*4);
  int*   counts = (int*)  alloc(NN*4);
  int*   rowptr = (int*)  alloc((NN+1)*4);
  int*   cursor = (int*)  alloc(NN*4);
  int*   col    = (int*)  alloc((size_t)NE*4);
  float* nrm    = (float*)alloc((size_t)NE*4);
  float* a_s    = (float*)alloc(NN*4);
  float* a_d    = (float*)alloc(NN*4);
  float* stats  = (float*)alloc(256*4);
  float* h1     = (float*)alloc(NN*4);
  float* xs     = (float*)alloc(NN*4);
  float* hfc    = (float*)alloc(256*4);

  const int G_N  = (NN + 255)/256;    // 150
  const int G_E  = (NE + 255)/256;    // 4688
  const int G_W4 = NN/4;              // 9583 (exact)
  const int G_L  = (NN + 31)/32;      // 1198

  // setup: degrees + CSR (once; reused by all 12 propagation passes)
  k_init<<<G_N, 256, 0, stream>>>(wdeg, counts);
  k_hist<<<G_E, 256, 0, stream>>>(dst, ew, wdeg, counts);
  k_dinv<<<G_N, 256, 0, stream>>>(wdeg, dinv);
  k_scan<<<1, 1024, 0, stream>>>(counts, rowptr, cursor);
  k_csr<<<G_E, 256, 0, stream>>>(src, dst, ew, dinv, cursor, col, nrm);

  // input layer: x = lrelu(gcn(concat_feats @ W_in))
  k_in_linear<<<G_W4, 256, 0, stream>>>(poi_idx, cat_idx, feat, poi_emb, cat_emb, W_in, h);
  k_gcn_prop<true><<<G_W4, 256, 0, stream>>>(h, rowptr, col, nrm, dinv, b_in, x);

  for (int i = 0; i < 5; i++){
    // GCN branch
    k_linear64<<<G_L, 256, 0, stream>>>(x, gcn_W + i*4096, h);
    k_gcn_prop<false><<<G_W4, 256, 0, stream>>>(h, rowptr, col, nrm, dinv, gcn_b + i*64, t);
    k_zero_stats<<<1, 128, 0, stream>>>(stats);
    k_colstats<<<128, 256, 0, stream>>>(t, stats);
    k_chan<<<1, 64, 0, stream>>>(gn_w + i*64, gn_a + i*64, stats);
    k_resid<<<G_W4, 256, 0, stream>>>(t, stats, gn_b + i*64, x);
    // GAT branch
    k_linear64<<<G_L, 256, 0, stream>>>(x, gat_W + i*4096, h);
    k_att<<<G_W4, 256, 0, stream>>>(h, att_s + i*64, att_d + i*64, a_s, a_d);
    k_gat_prop<<<G_W4, 256, 0, stream>>>(h, rowptr, col, a_s, a_d, gat_b + i*64, t);
    k_zero_stats<<<1, 128, 0, stream>>>(stats);
    k_colstats<<<128, 256, 0, stream>>>(t, stats);
    k_chan<<<1, 64, 0, stream>>>(gn_w + i*64, gn_a + i*64, stats);
    k_resid<<<G_W4, 256, 0, stream>>>(t, stats, gn_b + i*64, x);
  }

  // output head
  k_outlin<<<G_W4, 256, 0, stream>>>(x, W_out, h1);
  k_prop1<<<G_N, 256, 0, stream>>>(h1, rowptr, col, nrm, dinv, b_out, xs);
  k_fc1_init<<<1, 128, 0, stream>>>(fc1_b, hfc);
  k_fc1<<<256, 256, 0, stream>>>(xs, fc1_W, hfc);
  k_fc2<<<(POI + 255)/256, 256, 0, stream>>>(hfc, fc2_W, fc2_b, out);
}

// Round 2
// 1379.858 us; speedup vs baseline: 1.7638x; 1.7638x over previous
//
#include <hip/hip_runtime.h>

#define NN 38332
#define NE 1200000
#define CC 64
#define POI 38333

__device__ __forceinline__ float lrelu01(float v){ return v > 0.f ? v : 0.01f*v; }

// ---------------- setup: degrees + CSR ----------------
__global__ __launch_bounds__(256) void k_init(float* wdeg, int* counts){
  int i = blockIdx.x*256 + threadIdx.x;
  if (i < NN){ wdeg[i] = 1.0f; counts[i] = 0; }
}

__global__ __launch_bounds__(256) void k_hist(const int* __restrict__ dst,
                                              const float* __restrict__ w,
                                              float* wdeg, int* counts){
  int e = blockIdx.x*256 + threadIdx.x;
  if (e < NE){
    int d = dst[e];
    atomicAdd(&counts[d], 1);
    atomicAdd(&wdeg[d], w[e]);
  }
}

__global__ __launch_bounds__(256) void k_dinv(const float* __restrict__ wdeg, float* dinv){
  int i = blockIdx.x*256 + threadIdx.x;
  if (i < NN) dinv[i] = rsqrtf(wdeg[i]);
}

__global__ __launch_bounds__(1024) void k_scan(const int* __restrict__ counts,
                                               int* rowptr, int* cursor){
  __shared__ int part[1024];
  int tid = threadIdx.x;
  const int per = (NN + 1023)/1024;
  int base = tid*per;
  int s = 0;
  for (int k = 0; k < per; k++){ int i = base + k; if (i < NN) s += counts[i]; }
  part[tid] = s;
  __syncthreads();
  for (int off = 1; off < 1024; off <<= 1){
    int v = (tid >= off) ? part[tid-off] : 0;
    __syncthreads();
    part[tid] += v;
    __syncthreads();
  }
  int run = (tid == 0) ? 0 : part[tid-1];
  for (int k = 0; k < per; k++){
    int i = base + k;
    if (i < NN){ rowptr[i] = run; cursor[i] = run; run += counts[i]; }
  }
  if (tid == 1023) rowptr[NN] = run;
}

__global__ __launch_bounds__(256) void k_csr(const int* __restrict__ src,
                                             const int* __restrict__ dst,
                                             const float* __restrict__ ew,
                                             const float* __restrict__ dinv,
                                             int* cursor, int* __restrict__ col,
                                             int2* __restrict__ eg){
  int e = blockIdx.x*256 + threadIdx.x;
  if (e < NE){
    int s = src[e], d = dst[e];
    int p = atomicAdd(&cursor[d], 1);
    col[p] = s;
    eg[p] = make_int2(s, __float_as_int(dinv[s]*ew[e]*dinv[d]));
  }
}

// ---------------- dense projection: out[r][c] = sum_k emb[r][k]*W[k][c] ----------------
// 8 rows per wave; W chunk in registers; row-uniform scalar loads of emb.
template<int K>
__global__ __launch_bounds__(256) void k_proj(const float* __restrict__ emb,
                                              const float* __restrict__ W,
                                              float* __restrict__ outp, int rows){
  int lane = threadIdx.x & 63;
  int base = __builtin_amdgcn_readfirstlane(blockIdx.x*32 + (threadIdx.x >> 6)*8);
  float acc[8] = {0.f,0.f,0.f,0.f,0.f,0.f,0.f,0.f};
  constexpr int NCH = (K + 63)/64;
  #pragma unroll
  for (int ch = 0; ch < NCH; ++ch){
    float Wreg[64];
    #pragma unroll
    for (int j = 0; j < 64; ++j)
      Wreg[j] = (ch*64 + j < K) ? W[(ch*64 + j)*64 + lane] : 0.f;
    #pragma unroll
    for (int r = 0; r < 8; ++r){
      int row = base + r;
      if (row < rows){
        const float* er = emb + (size_t)row*K + ch*64;
        #pragma unroll
        for (int j = 0; j < 64; ++j)
          if (ch*64 + j < K) acc[r] = fmaf(er[j], Wreg[j], acc[r]);
      }
    }
  }
  #pragma unroll
  for (int r = 0; r < 8; ++r){
    int row = base + r;
    if (row < rows) outp[(size_t)row*64 + lane] = acc[r];
  }
}

// gather: h_in[n][c] = poi_proj[pi[n]][c] + cat_proj[ci[n]][c] + feat[n]·Wf[:,c]
__global__ __launch_bounds__(256) void k_gather(const int* __restrict__ poi_idx,
                                                const int* __restrict__ cat_idx,
                                                const float* __restrict__ feat,
                                                const float* __restrict__ pproj,
                                                const float* __restrict__ cproj,
                                                const float* __restrict__ Wf,
                                                float* __restrict__ outh){
  int i = blockIdx.x*256 + threadIdx.x;   // grid exact: NN*64 % 256 == 0
  int n = i >> 6, c = i & 63;
  float f0 = feat[n*3], f1 = feat[n*3+1], f2 = feat[n*3+2];
  float v = pproj[(size_t)poi_idx[n]*64 + c] + cproj[(size_t)cat_idx[n]*64 + c];
  v = fmaf(f0, Wf[c], v);
  v = fmaf(f1, Wf[64 + c], v);
  v = fmaf(f2, Wf[128 + c], v);
  outh[i] = v;
}

// ---------------- 64x64 linear, W column in registers; optional fused attention dots ----------------
template<bool ATT>
__global__ __launch_bounds__(256) void k_lin64(const float* __restrict__ x,
                                               const float* __restrict__ W,
                                               const float* __restrict__ att_src,
                                               const float* __restrict__ att_dst,
                                               float* __restrict__ h,
                                               float* __restrict__ a_s,
                                               float* __restrict__ a_d){
  int lane = threadIdx.x & 63;
  int base = __builtin_amdgcn_readfirstlane(blockIdx.x*32 + (threadIdx.x >> 6)*8);
  float Wreg[64];
  #pragma unroll
  for (int j = 0; j < 64; ++j) Wreg[j] = W[j*64 + lane];
  float as_l = 0.f, ad_l = 0.f;
  if (ATT){ as_l = att_src[lane]; ad_l = att_dst[lane]; }
  #pragma unroll
  for (int r = 0; r < 8; ++r){
    int row = base + r;
    if (row < NN){
      const float* er = x + (size_t)row*64;
      float acc = 0.f;
      #pragma unroll
      for (int j = 0; j < 64; ++j) acc = fmaf(er[j], Wreg[j], acc);
      h[(size_t)row*64 + lane] = acc;
      if (ATT){
        float s1 = acc*as_l, s2 = acc*ad_l;
        #pragma unroll
        for (int off = 32; off; off >>= 1){ s1 += __shfl_xor(s1, off); s2 += __shfl_xor(s2, off); }
        if (lane == 0){ a_s[row] = s1; a_d[row] = s2; }
      }
    }
  }
}

// ---------------- GCN propagation ----------------
template<bool DO_LRELU>
__global__ __launch_bounds__(256) void k_gcn_prop(const float* __restrict__ h,
                                                  const int* __restrict__ rowptr,
                                                  const int2* __restrict__ eg,
                                                  const float* __restrict__ dinv,
                                                  const float* __restrict__ b,
                                                  float* __restrict__ out){
  int lane = threadIdx.x & 63;
  int n = __builtin_amdgcn_readfirstlane(blockIdx.x*4 + (threadIdx.x >> 6));
  int beg = rowptr[n], end = rowptr[n+1];
  float di = dinv[n];
  float a0 = di*di*h[(size_t)n*64 + lane], a1 = 0.f, a2 = 0.f, a3 = 0.f;
  int e = beg;
  for (; e + 4 <= end; e += 4){
    int2 p0 = eg[e], p1 = eg[e+1], p2 = eg[e+2], p3 = eg[e+3];
    a0 = fmaf(__int_as_float(p0.y), h[(size_t)p0.x*64 + lane], a0);
    a1 = fmaf(__int_as_float(p1.y), h[(size_t)p1.x*64 + lane], a1);
    a2 = fmaf(__int_as_float(p2.y), h[(size_t)p2.x*64 + lane], a2);
    a3 = fmaf(__int_as_float(p3.y), h[(size_t)p3.x*64 + lane], a3);
  }
  for (; e < end; ++e){
    int2 p = eg[e];
    a0 = fmaf(__int_as_float(p.y), h[(size_t)p.x*64 + lane], a0);
  }
  float acc = (a0 + a1) + (a2 + a3) + b[lane];
  if (DO_LRELU) acc = lrelu01(acc);
  out[(size_t)n*64 + lane] = acc;
}

// ---------------- GAT propagation (register-resident softmax, deg<=64 fast path) ----------------
__global__ __launch_bounds__(256) void k_gat_prop(const float* __restrict__ h,
                                                  const int* __restrict__ rowptr,
                                                  const int* __restrict__ col,
                                                  const float* __restrict__ a_s,
                                                  const float* __restrict__ a_d,
                                                  const float* __restrict__ b,
                                                  float* __restrict__ out){
  int lane = threadIdx.x & 63;
  int n = __builtin_amdgcn_readfirstlane(blockIdx.x*4 + (threadIdx.x >> 6));
  int beg = rowptr[n], end = rowptr[n+1];
  int deg = end - beg;
  float ad = a_d[n];
  float se = a_s[n] + ad; se = se > 0.f ? se : 0.2f*se;
  float acc, zinv;
  if (deg <= 64){
    int s = 0; float v = -1e30f;
    if (lane < deg){
      s = col[beg + lane];
      v = a_s[s] + ad; v = v > 0.f ? v : 0.2f*v;
    }
    float m = fmaxf(se, v);
    #pragma unroll
    for (int off = 32; off; off >>= 1) m = fmaxf(m, __shfl_xor(m, off));
    float ev = (lane < deg) ? __expf(v - m) : 0.f;
    float z = ev;
    #pragma unroll
    for (int off = 32; off; off >>= 1) z += __shfl_xor(z, off);
    float es = __expf(se - m);
    z += es;
    zinv = 1.0f/(z + 1e-16f);
    acc = es*h[(size_t)n*64 + lane];
    for (int j = 0; j < deg; ++j){
      float w = __shfl(ev, j);
      int   sj = __shfl(s, j);
      acc = fmaf(w, h[(size_t)sj*64 + lane], acc);
    }
  } else {
    float m = se;
    for (int e = beg + lane; e < end; e += 64){
      float v = a_s[col[e]] + ad; v = v > 0.f ? v : 0.2f*v;
      m = fmaxf(m, v);
    }
    #pragma unroll
    for (int off = 32; off; off >>= 1) m = fmaxf(m, __shfl_xor(m, off));
    float z = 0.f;
    for (int e = beg + lane; e < end; e += 64){
      float v = a_s[col[e]] + ad; v = v > 0.f ? v : 0.2f*v;
      z += __expf(v - m);
    }
    #pragma unroll
    for (int off = 32; off; off >>= 1) z += __shfl_xor(z, off);
    float es = __expf(se - m);
    z += es;
    zinv = 1.0f/(z + 1e-16f);
    acc = es*h[(size_t)n*64 + lane];
    for (int e = beg; e < end; ++e){
      int sj = col[e];
      float v = a_s[sj] + ad; v = v > 0.f ? v : 0.2f*v;
      acc = fmaf(__expf(v - m), h[(size_t)sj*64 + lane], acc);
    }
  }
  out[(size_t)n*64 + lane] = acc*zinv + b[lane];
}

// ---------------- GraphNorm ----------------
__global__ __launch_bounds__(128) void k_zero_stats(float* stats){
  if (threadIdx.x < 128) stats[threadIdx.x] = 0.f;
}

__global__ __launch_bounds__(256) void k_colstats(const float* __restrict__ t, float* stats){
  int lane = threadIdx.x & 63;
  int sub  = threadIdx.x >> 6;
  float s = 0.f, s2 = 0.f;
  for (int n = blockIdx.x*4 + sub; n < NN; n += gridDim.x*4){
    float v = t[(size_t)n*64 + lane];
    s += v; s2 = fmaf(v, v, s2);
  }
  __shared__ float ls[256], ls2[256];
  ls[threadIdx.x] = s; ls2[threadIdx.x] = s2;
  __syncthreads();
  if (threadIdx.x < 64){
    s  = ls[threadIdx.x]  + ls[threadIdx.x+64]  + ls[threadIdx.x+128]  + ls[threadIdx.x+192];
    s2 = ls2[threadIdx.x] + ls2[threadIdx.x+64] + ls2[threadIdx.x+128] + ls2[threadIdx.x+192];
    atomicAdd(&stats[threadIdx.x], s);
    atomicAdd(&stats[64 + threadIdx.x], s2);
  }
}

__global__ __launch_bounds__(64) void k_chan(const float* __restrict__ gw,
                                             const float* __restrict__ ga,
                                             float* stats){
  int c = threadIdx.x;
  const float invN = 1.0f/(float)NN;
  float m  = stats[c]*invN;
  float ms = stats[64 + c]*invN;
  float a  = ga[c];
  float var = ms - m*m*a*(2.0f - a);
  stats[128 + c] = rsqrtf(var + 1e-5f)*gw[c];  // coef
  stats[192 + c] = a*m;                        // shift
}

__global__ __launch_bounds__(256) void k_resid4(const float4* __restrict__ t4,
                                                const float* __restrict__ stats,
                                                const float* __restrict__ gb,
                                                float4* __restrict__ x4){
  int i = blockIdx.x*256 + threadIdx.x;
  if (i < NN*16){
    int c = (i & 15)*4;
    float4 tv = t4[i];
    float4 xv = x4[i];
    float4 cf = *(const float4*)&stats[128 + c];
    float4 sh = *(const float4*)&stats[192 + c];
    float4 gv = *(const float4*)&gb[c];
    xv.x += lrelu01((tv.x - sh.x)*cf.x + gv.x);
    xv.y += lrelu01((tv.y - sh.y)*cf.y + gv.y);
    xv.z += lrelu01((tv.z - sh.z)*cf.z + gv.z);
    xv.w += lrelu01((tv.w - sh.w)*cf.w + gv.w);
    x4[i] = xv;
  }
}

// ---------------- output head ----------------
__global__ __launch_bounds__(256) void k_outlin(const float* __restrict__ x,
                                                const float* __restrict__ Wout,
                                                float* __restrict__ h1){
  int lane = threadIdx.x & 63, wave = threadIdx.x >> 6;
  int n = blockIdx.x*4 + wave;
  if (n >= NN) return;
  float v = x[(size_t)n*64 + lane]*Wout[lane];
  #pragma unroll
  for (int off = 32; off; off >>= 1) v += __shfl_xor(v, off);
  if (lane == 0) h1[n] = v;
}

__global__ __launch_bounds__(256) void k_prop1(const float* __restrict__ h1,
                                               const int* __restrict__ rowptr,
                                               const int2* __restrict__ eg,
                                               const float* __restrict__ dinv,
                                               const float* __restrict__ b_out,
                                               float* __restrict__ xs){
  int n = blockIdx.x*256 + threadIdx.x;
  if (n >= NN) return;
  float di = dinv[n];
  float acc = di*di*h1[n];
  int beg = rowptr[n], end = rowptr[n+1];
  for (int e = beg; e < end; e++){
    int2 p = eg[e];
    acc = fmaf(__int_as_float(p.y), h1[p.x], acc);
  }
  acc += b_out[0];
  xs[n] = lrelu01(acc);
}

__global__ __launch_bounds__(128) void k_fc1_init(const float* __restrict__ fc1_b, float* hfc){
  if (threadIdx.x < 128) hfc[threadIdx.x] = fc1_b[threadIdx.x];
}

__global__ __launch_bounds__(256) void k_fc1(const float* __restrict__ xs,
                                             const float* __restrict__ W,
                                             float* hfc){
  int j = threadIdx.x & 127, half = threadIdx.x >> 7;
  float acc = 0.f;
  for (int n = blockIdx.x*2 + half; n < NN; n += gridDim.x*2)
    acc = fmaf(xs[n], W[(size_t)n*128 + j], acc);
  __shared__ float ls[256];
  ls[threadIdx.x] = acc;
  __syncthreads();
  if (threadIdx.x < 128) atomicAdd(&hfc[j], ls[j] + ls[128 + j]);
}

__global__ __launch_bounds__(256) void k_fc2(const float* __restrict__ hfc,
                                             const float* __restrict__ W2,
                                             const float* __restrict__ b2,
                                             float* __restrict__ out){
  __shared__ float hs[128];
  if (threadIdx.x < 128){ float v = hfc[threadIdx.x]; hs[threadIdx.x] = v > 0.f ? v : 0.f; }
  __syncthreads();
  int p = blockIdx.x*256 + threadIdx.x;
  if (p < POI){
    float acc = b2[p];
    #pragma unroll
    for (int j = 0; j < 128; j++) acc = fmaf(hs[j], W2[(size_t)j*POI + p], acc);
    out[p] = acc > 0.f ? acc : 0.f;
  }
}

// ---------------- launch ----------------
extern "C" void kernel_launch(void* const* d_in, const int* in_sizes, int n_in,
                              void* d_out, int out_size, void* d_ws, size_t ws_size,
                              hipStream_t stream) {
  const int*   poi_idx = (const int*)d_in[0];
  const int*   cat_idx = (const int*)d_in[1];
  const float* feat    = (const float*)d_in[2];
  const int*   eidx    = (const int*)d_in[3];
  const int*   src     = eidx;
  const int*   dst     = eidx + NE;
  const float* ew      = (const float*)d_in[4];
  const float* poi_emb = (const float*)d_in[5];
  const float* cat_emb = (const float*)d_in[6];
  const float* W_in    = (const float*)d_in[7];
  const float* b_in    = (const float*)d_in[8];
  const float* gcn_W   = (const float*)d_in[9];
  const float* gcn_b   = (const float*)d_in[10];
  const float* gn_w    = (const float*)d_in[11];
  const float* gn_b    = (const float*)d_in[12];
  const float* gn_a    = (const float*)d_in[13];
  const float* gat_W   = (const float*)d_in[14];
  const float* att_s   = (const float*)d_in[15];
  const float* att_d   = (const float*)d_in[16];
  const float* gat_b   = (const float*)d_in[17];
  const float* W_out   = (const float*)d_in[18];
  const float* b_out   = (const float*)d_in[19];
  const float* fc1_W   = (const float*)d_in[20];
  const float* fc1_b   = (const float*)d_in[21];
  const float* fc2_W   = (const float*)d_in[22];
  const float* fc2_b   = (const float*)d_in[23];
  float* out = (float*)d_out;

  char* p = (char*)d_ws;
  auto alloc = [&](size_t bytes){ void* r = (void*)p; p += (bytes + 255) & ~(size_t)255; return r; };
  float* x      = (float*)alloc((size_t)NN*64*4);
  float* t      = (float*)alloc((size_t)NN*64*4);
  float* h      = (float*)alloc((size_t)POI*64*4);   // also holds poi_proj (POI rows)
  float* cproj  = (float*)alloc((size_t)400*64*4);
  float* dinv   = (float*)alloc(NN*4);
  float* wdeg   = (float*)alloc(NN*4);
  int*   counts = (int*)  alloc(NN*4);
  int*   rowptr = (int*)  alloc((NN+1)*4);
  int*   cursor = (int*)  alloc(NN*4);
  int*   col    = (int*)  alloc((size_t)NE*4);
  int2*  eg     = (int2*) alloc((size_t)NE*8);
  float* a_s    = (float*)alloc(NN*4);
  float* a_d    = (float*)alloc(NN*4);
  float* stats  = (float*)alloc(256*4);
  float* h1     = (float*)alloc(NN*4);
  float* xs     = (float*)alloc(NN*4);
  float* hfc    = (float*)alloc(256*4);

  const int G_N   = (NN + 255)/256;     // 150
  const int G_E   = (NE + 255)/256;     // 4688
  const int G_W4  = NN/4;               // 9583 (exact)
  const int G_L   = (NN + 31)/32;       // 1199
  const int G_PP  = (POI + 31)/32;      // 1199
  const int G_EL  = NN*64/256;          // 9583 (exact)
  const int G_R4  = (NN*16 + 255)/256;  // 2396

  // setup: degrees + CSR (reused by all 12 propagation passes)
  k_init<<<G_N, 256, 0, stream>>>(wdeg, counts);
  k_hist<<<G_E, 256, 0, stream>>>(dst, ew, wdeg, counts);
  k_dinv<<<G_N, 256, 0, stream>>>(wdeg, dinv);
  k_scan<<<1, 1024, 0, stream>>>(counts, rowptr, cursor);
  k_csr<<<G_E, 256, 0, stream>>>(src, dst, ew, dinv, cursor, col, eg);

  // input layer: precompute projections, gather, then GCN prop
  k_proj<300><<<G_PP, 256, 0, stream>>>(poi_emb, W_in, h, POI);
  k_proj<100><<<13, 256, 0, stream>>>(cat_emb, W_in + 300*64, cproj, 400);
  k_gather<<<G_EL, 256, 0, stream>>>(poi_idx, cat_idx, feat, h, cproj, W_in + 400*64, t);
  k_gcn_prop<true><<<G_W4, 256, 0, stream>>>(t, rowptr, eg, dinv, b_in, x);

  for (int i = 0; i < 5; i++){
    // GCN branch
    k_lin64<false><<<G_L, 256, 0, stream>>>(x, gcn_W + i*4096, nullptr, nullptr, h, nullptr, nullptr);
    k_gcn_prop<false><<<G_W4, 256, 0, stream>>>(h, rowptr, eg, dinv, gcn_b + i*64, t);
    k_zero_stats<<<1, 128, 0, stream>>>(stats);
    k_colstats<<<256, 256, 0, stream>>>(t, stats);
    k_chan<<<1, 64, 0, stream>>>(gn_w + i*64, gn_a + i*64, stats);
    k_resid4<<<G_R4, 256, 0, stream>>>((const float4*)t, stats, gn_b + i*64, (float4*)x);
    // GAT branch (attention dots fused into the linear)
    k_lin64<true><<<G_L, 256, 0, stream>>>(x, gat_W + i*4096, att_s + i*64, att_d + i*64, h, a_s, a_d);
    k_gat_prop<<<G_W4, 256, 0, stream>>>(h, rowptr, col, a_s, a_d, gat_b + i*64, t);
    k_zero_stats<<<1, 128, 0, stream>>>(stats);
    k_colstats<<<256, 256, 0, stream>>>(t, stats);
    k_chan<<<1, 64, 0, stream>>>(gn_w + i*64, gn_a + i*64, stats);
    k_resid4<<<G_R4, 256, 0, stream>>>((const float4*)t, stats, gn_b + i*64, (float4*)x);
  }

  // output head
  k_outlin<<<G_W4, 256, 0, stream>>>(x, W_out, h1);
  k_prop1<<<G_N, 256, 0, stream>>>(h1, rowptr, eg, dinv, b_out, xs);
  k_fc1_init<<<1, 128, 0, stream>>>(fc1_b, hfc);
  k_fc1<<<256, 256, 0, stream>>>(xs, fc1_W, hfc);
  k_fc2<<<(POI + 255)/256, 256, 0, stream>>>(hfc, fc2_W, fc2_b, out);
}

// Round 3
// 1349.059 us; speedup vs baseline: 1.8041x; 1.0228x over previous
//
#include <hip/hip_runtime.h>

#define NN 38332
#define NE 1200000
#define POI 38333
#define NWG 32
#define CHUNK (NE/NWG)   // 37500 exactly

__device__ __forceinline__ float lrelu01(float v){ return v > 0.f ? v : 0.01f*v; }

// ---------------- setup phase A: LDS-privatized histogram ----------------
__global__ __launch_bounds__(1024) void k_hist(const int* __restrict__ dst,
                                               int* __restrict__ partial){
  __shared__ int hist[NN];
  for (int i = threadIdx.x; i < NN; i += 1024) hist[i] = 0;
  __syncthreads();
  int base = blockIdx.x*CHUNK;
  for (int k = threadIdx.x; k < CHUNK; k += 1024)
    atomicAdd(&hist[dst[base + k]], 1);
  __syncthreads();
  for (int i = threadIdx.x; i < NN; i += 1024)
    partial[blockIdx.x*NN + i] = hist[i];
}

// ---------------- phase B1: per-bin WG exclusive prefix + total counts ----------------
__global__ __launch_bounds__(256) void k_b1(int* __restrict__ partial, int* __restrict__ counts){
  int bin = blockIdx.x*256 + threadIdx.x;
  if (bin < NN){
    int run = 0;
    #pragma unroll 4
    for (int wg = 0; wg < NWG; ++wg){
      int v = partial[wg*NN + bin];
      partial[wg*NN + bin] = run;
      run += v;
    }
    counts[bin] = run;
  }
}

// ---------------- phase B2: rowptr scan (single WG) ----------------
__global__ __launch_bounds__(1024) void k_scan(const int* __restrict__ counts, int* rowptr){
  __shared__ int part[1024];
  int tid = threadIdx.x;
  const int per = (NN + 1023)/1024;   // 38
  int base = tid*per;
  int s = 0;
  for (int k = 0; k < per; k++){ int i = base + k; if (i < NN) s += counts[i]; }
  part[tid] = s;
  __syncthreads();
  for (int off = 1; off < 1024; off <<= 1){
    int v = (tid >= off) ? part[tid-off] : 0;
    __syncthreads();
    part[tid] += v;
    __syncthreads();
  }
  int run = (tid == 0) ? 0 : part[tid-1];
  for (int k = 0; k < per; k++){
    int i = base + k;
    if (i < NN){ rowptr[i] = run; run += counts[i]; }
  }
  if (tid == 1023) rowptr[NN] = run;
}

// ---------------- phase C: scatter with LDS cursors ----------------
__global__ __launch_bounds__(1024) void k_scatter(const int* __restrict__ src,
                                                  const int* __restrict__ dst,
                                                  const float* __restrict__ ew,
                                                  const int* __restrict__ rowptr,
                                                  const int* __restrict__ partial,
                                                  int2* __restrict__ cw){
  __shared__ int cur[NN];
  for (int i = threadIdx.x; i < NN; i += 1024)
    cur[i] = rowptr[i] + partial[blockIdx.x*NN + i];
  __syncthreads();
  int base = blockIdx.x*CHUNK;
  for (int k = threadIdx.x; k < CHUNK; k += 1024){
    int e = base + k;
    int d = dst[e];
    int pos = atomicAdd(&cur[d], 1);
    cw[pos] = make_int2(src[e], __float_as_int(ew[e]));
  }
}

// ---------------- phase D: dinv from per-node weight sums ----------------
__global__ __launch_bounds__(256) void k_dinv(const int* __restrict__ rowptr,
                                              const int2* __restrict__ cw,
                                              float* __restrict__ dinv){
  int lane = threadIdx.x & 63;
  int n = blockIdx.x*4 + (threadIdx.x >> 6);   // NN % 4 == 0
  int beg = rowptr[n], end = rowptr[n+1];
  float s = 0.f;
  for (int e = beg + lane; e < end; e += 64) s += __int_as_float(cw[e].y);
  #pragma unroll
  for (int off = 32; off; off >>= 1) s += __shfl_xor(s, off);
  if (lane == 0) dinv[n] = rsqrtf(1.0f + s);
}

// ---------------- phase E: w -> symmetric norm in place ----------------
__global__ __launch_bounds__(256) void k_scale(const int* __restrict__ rowptr,
                                               const float* __restrict__ dinv,
                                               int2* __restrict__ cw){
  int lane = threadIdx.x & 63;
  int n = blockIdx.x*4 + (threadIdx.x >> 6);
  float dn = dinv[n];
  int beg = rowptr[n], end = rowptr[n+1];
  for (int e = beg + lane; e < end; e += 64){
    int2 p = cw[e];
    cw[e].y = __float_as_int(dinv[p.x]*__int_as_float(p.y)*dn);
  }
}

// ---------------- dense projection: out[r][c] = sum_k emb[r][k]*W[k][c] ----------------
template<int K>
__global__ __launch_bounds__(256) void k_proj(const float* __restrict__ emb,
                                              const float* __restrict__ W,
                                              float* __restrict__ outp, int rows){
  int lane = threadIdx.x & 63;
  int base = __builtin_amdgcn_readfirstlane(blockIdx.x*32 + (threadIdx.x >> 6)*8);
  float acc[8] = {0.f,0.f,0.f,0.f,0.f,0.f,0.f,0.f};
  constexpr int NCH = (K + 63)/64;
  #pragma unroll
  for (int ch = 0; ch < NCH; ++ch){
    float Wreg[64];
    #pragma unroll
    for (int j = 0; j < 64; ++j)
      Wreg[j] = (ch*64 + j < K) ? W[(ch*64 + j)*64 + lane] : 0.f;
    #pragma unroll
    for (int r = 0; r < 8; ++r){
      int row = base + r;
      if (row < rows){
        const float* er = emb + (size_t)row*K + ch*64;
        #pragma unroll
        for (int j = 0; j < 64; ++j)
          if (ch*64 + j < K) acc[r] = fmaf(er[j], Wreg[j], acc[r]);
      }
    }
  }
  #pragma unroll
  for (int r = 0; r < 8; ++r){
    int row = base + r;
    if (row < rows) outp[(size_t)row*64 + lane] = acc[r];
  }
}

__global__ __launch_bounds__(256) void k_gather(const int* __restrict__ poi_idx,
                                                const int* __restrict__ cat_idx,
                                                const float* __restrict__ feat,
                                                const float* __restrict__ pproj,
                                                const float* __restrict__ cproj,
                                                const float* __restrict__ Wf,
                                                float* __restrict__ outh){
  int i = blockIdx.x*256 + threadIdx.x;   // NN*64 % 256 == 0
  int n = i >> 6, c = i & 63;
  float f0 = feat[n*3], f1 = feat[n*3+1], f2 = feat[n*3+2];
  float v = pproj[(size_t)poi_idx[n]*64 + c] + cproj[(size_t)cat_idx[n]*64 + c];
  v = fmaf(f0, Wf[c], v);
  v = fmaf(f1, Wf[64 + c], v);
  v = fmaf(f2, Wf[128 + c], v);
  outh[i] = v;
}

// ---------------- fused [graphnorm-residual] + 64x64 linear (+ attention dots) ----------------
template<bool ATT, bool RESID>
__global__ __launch_bounds__(256) void k_lin64f(float* __restrict__ x,
                                                const float* __restrict__ t,
                                                const float* __restrict__ stats,
                                                const float* __restrict__ gb,
                                                const float* __restrict__ W,
                                                const float* __restrict__ att_src,
                                                const float* __restrict__ att_dst,
                                                float* __restrict__ h,
                                                float* __restrict__ a_s,
                                                float* __restrict__ a_d){
  int lane = threadIdx.x & 63;
  int base = blockIdx.x*32 + (threadIdx.x >> 6)*8;
  float Wreg[64];
  #pragma unroll
  for (int j = 0; j < 64; ++j) Wreg[j] = W[j*64 + lane];
  float coef = 0.f, shift = 0.f, gbv = 0.f;
  if (RESID){ coef = stats[128 + lane]; shift = stats[192 + lane]; gbv = gb[lane]; }
  float as_l = 0.f, ad_l = 0.f;
  if (ATT){ as_l = att_src[lane]; ad_l = att_dst[lane]; }
  #pragma unroll
  for (int r = 0; r < 8; ++r){
    int row = base + r;
    if (row < NN){
      float xn = x[(size_t)row*64 + lane];
      if (RESID){
        float tv = t[(size_t)row*64 + lane];
        xn += lrelu01((tv - shift)*coef + gbv);
        x[(size_t)row*64 + lane] = xn;
      }
      int xi = __float_as_int(xn);
      float acc = 0.f;
      #pragma unroll
      for (int j = 0; j < 64; ++j)
        acc = fmaf(__int_as_float(__builtin_amdgcn_readlane(xi, j)), Wreg[j], acc);
      h[(size_t)row*64 + lane] = acc;
      if (ATT){
        float s1 = acc*as_l, s2 = acc*ad_l;
        #pragma unroll
        for (int off = 32; off; off >>= 1){ s1 += __shfl_xor(s1, off); s2 += __shfl_xor(s2, off); }
        if (lane == 0){ a_s[row] = s1; a_d[row] = s2; }
      }
    }
  }
}

// ---------------- GCN propagation (8-deep ILP) ----------------
template<bool DO_LRELU>
__global__ __launch_bounds__(256) void k_gcn_prop(const float* __restrict__ h,
                                                  const int* __restrict__ rowptr,
                                                  const int2* __restrict__ cw,
                                                  const float* __restrict__ dinv,
                                                  const float* __restrict__ b,
                                                  float* __restrict__ out){
  int lane = threadIdx.x & 63;
  int n = __builtin_amdgcn_readfirstlane(blockIdx.x*4 + (threadIdx.x >> 6));
  int beg = rowptr[n], end = rowptr[n+1];
  float di = dinv[n];
  float a0 = di*di*h[(size_t)n*64 + lane];
  float a1=0.f,a2=0.f,a3=0.f,a4=0.f,a5=0.f,a6=0.f,a7=0.f;
  int e = beg;
  for (; e + 8 <= end; e += 8){
    int2 p0=cw[e],p1=cw[e+1],p2=cw[e+2],p3=cw[e+3],p4=cw[e+4],p5=cw[e+5],p6=cw[e+6],p7=cw[e+7];
    a0 = fmaf(__int_as_float(p0.y), h[(size_t)p0.x*64 + lane], a0);
    a1 = fmaf(__int_as_float(p1.y), h[(size_t)p1.x*64 + lane], a1);
    a2 = fmaf(__int_as_float(p2.y), h[(size_t)p2.x*64 + lane], a2);
    a3 = fmaf(__int_as_float(p3.y), h[(size_t)p3.x*64 + lane], a3);
    a4 = fmaf(__int_as_float(p4.y), h[(size_t)p4.x*64 + lane], a4);
    a5 = fmaf(__int_as_float(p5.y), h[(size_t)p5.x*64 + lane], a5);
    a6 = fmaf(__int_as_float(p6.y), h[(size_t)p6.x*64 + lane], a6);
    a7 = fmaf(__int_as_float(p7.y), h[(size_t)p7.x*64 + lane], a7);
  }
  for (; e < end; ++e){
    int2 p = cw[e];
    a0 = fmaf(__int_as_float(p.y), h[(size_t)p.x*64 + lane], a0);
  }
  float acc = ((a0+a1)+(a2+a3)) + ((a4+a5)+(a6+a7)) + b[lane];
  if (DO_LRELU) acc = lrelu01(acc);
  out[(size_t)n*64 + lane] = acc;
}

// ---------------- GAT propagation ----------------
__global__ __launch_bounds__(256) void k_gat_prop(const float* __restrict__ h,
                                                  const int* __restrict__ rowptr,
                                                  const int2* __restrict__ cw,
                                                  const float* __restrict__ a_s,
                                                  const float* __restrict__ a_d,
                                                  const float* __restrict__ b,
                                                  float* __restrict__ out){
  int lane = threadIdx.x & 63;
  int n = __builtin_amdgcn_readfirstlane(blockIdx.x*4 + (threadIdx.x >> 6));
  int beg = rowptr[n], end = rowptr[n+1];
  int deg = end - beg;
  float ad = a_d[n];
  float se = a_s[n] + ad; se = se > 0.f ? se : 0.2f*se;
  float acc, zinv;
  if (deg <= 64){
    int s = 0; float v = -1e30f;
    if (lane < deg){
      s = cw[beg + lane].x;
      v = a_s[s] + ad; v = v > 0.f ? v : 0.2f*v;
    }
    float m = fmaxf(se, v);
    #pragma unroll
    for (int off = 32; off; off >>= 1) m = fmaxf(m, __shfl_xor(m, off));
    float ev = (lane < deg) ? __expf(v - m) : 0.f;
    float z = ev;
    #pragma unroll
    for (int off = 32; off; off >>= 1) z += __shfl_xor(z, off);
    float es = __expf(se - m);
    z += es;
    zinv = 1.0f/(z + 1e-16f);
    acc = es*h[(size_t)n*64 + lane];
    float acc2 = 0.f;
    int j = 0;
    for (; j + 2 <= deg; j += 2){
      float w0 = __shfl(ev, j),   w1 = __shfl(ev, j+1);
      int   s0 = __shfl(s,  j),   s1 = __shfl(s,  j+1);
      acc  = fmaf(w0, h[(size_t)s0*64 + lane], acc);
      acc2 = fmaf(w1, h[(size_t)s1*64 + lane], acc2);
    }
    if (j < deg){
      float w0 = __shfl(ev, j); int s0 = __shfl(s, j);
      acc = fmaf(w0, h[(size_t)s0*64 + lane], acc);
    }
    acc += acc2;
  } else {
    float m = se;
    for (int e = beg + lane; e < end; e += 64){
      float v = a_s[cw[e].x] + ad; v = v > 0.f ? v : 0.2f*v;
      m = fmaxf(m, v);
    }
    #pragma unroll
    for (int off = 32; off; off >>= 1) m = fmaxf(m, __shfl_xor(m, off));
    float z = 0.f;
    for (int e = beg + lane; e < end; e += 64){
      float v = a_s[cw[e].x] + ad; v = v > 0.f ? v : 0.2f*v;
      z += __expf(v - m);
    }
    #pragma unroll
    for (int off = 32; off; off >>= 1) z += __shfl_xor(z, off);
    float es = __expf(se - m);
    z += es;
    zinv = 1.0f/(z + 1e-16f);
    acc = es*h[(size_t)n*64 + lane];
    for (int e = beg; e < end; ++e){
      int sj = cw[e].x;
      float v = a_s[sj] + ad; v = v > 0.f ? v : 0.2f*v;
      acc = fmaf(__expf(v - m), h[(size_t)sj*64 + lane], acc);
    }
  }
  out[(size_t)n*64 + lane] = acc*zinv + b[lane];
}

// ---------------- GraphNorm stats: per-block partials (no atomics) ----------------
__global__ __launch_bounds__(256) void k_colstats(const float* __restrict__ t,
                                                  float* __restrict__ pstats){
  int lane = threadIdx.x & 63;
  int sub  = threadIdx.x >> 6;
  float s = 0.f, s2 = 0.f;
  for (int n = blockIdx.x*4 + sub; n < NN; n += gridDim.x*4){
    float v = t[(size_t)n*64 + lane];
    s += v; s2 = fmaf(v, v, s2);
  }
  __shared__ float ls[256], ls2[256];
  ls[threadIdx.x] = s; ls2[threadIdx.x] = s2;
  __syncthreads();
  if (threadIdx.x < 64){
    s  = ls[threadIdx.x]  + ls[threadIdx.x+64]  + ls[threadIdx.x+128]  + ls[threadIdx.x+192];
    s2 = ls2[threadIdx.x] + ls2[threadIdx.x+64] + ls2[threadIdx.x+128] + ls2[threadIdx.x+192];
    pstats[blockIdx.x*128 + threadIdx.x]      = s;
    pstats[blockIdx.x*128 + 64 + threadIdx.x] = s2;
  }
}

__global__ __launch_bounds__(64) void k_chan(const float* __restrict__ pstats,
                                             const float* __restrict__ gw,
                                             const float* __restrict__ ga,
                                             float* __restrict__ stats){
  int c = threadIdx.x;
  float s = 0.f, s2 = 0.f;
  for (int blk = 0; blk < 64; ++blk){
    s  += pstats[blk*128 + c];
    s2 += pstats[blk*128 + 64 + c];
  }
  const float invN = 1.0f/(float)NN;
  float m  = s*invN;
  float ms = s2*invN;
  float a  = ga[c];
  float var = ms - m*m*a*(2.0f - a);
  stats[128 + c] = rsqrtf(var + 1e-5f)*gw[c];  // coef
  stats[192 + c] = a*m;                        // shift
}

// ---------------- output head: fused resid + dot ----------------
__global__ __launch_bounds__(256) void k_outlinf(const float* __restrict__ x,
                                                 const float* __restrict__ t,
                                                 const float* __restrict__ stats,
                                                 const float* __restrict__ gb,
                                                 const float* __restrict__ Wout,
                                                 float* __restrict__ h1){
  int lane = threadIdx.x & 63, wave = threadIdx.x >> 6;
  int n = blockIdx.x*4 + wave;
  float coef = stats[128 + lane], shift = stats[192 + lane], gbv = gb[lane];
  float xn = x[(size_t)n*64 + lane];
  float tv = t[(size_t)n*64 + lane];
  xn += lrelu01((tv - shift)*coef + gbv);
  float v = xn*Wout[lane];
  #pragma unroll
  for (int off = 32; off; off >>= 1) v += __shfl_xor(v, off);
  if (lane == 0) h1[n] = v;
}

__global__ __launch_bounds__(256) void k_prop1(const float* __restrict__ h1,
                                               const int* __restrict__ rowptr,
                                               const int2* __restrict__ cw,
                                               const float* __restrict__ dinv,
                                               const float* __restrict__ b_out,
                                               float* __restrict__ xs){
  int n = blockIdx.x*256 + threadIdx.x;
  if (n >= NN) return;
  float di = dinv[n];
  float acc = di*di*h1[n];
  int beg = rowptr[n], end = rowptr[n+1];
  for (int e = beg; e < end; e++){
    int2 p = cw[e];
    acc = fmaf(__int_as_float(p.y), h1[p.x], acc);
  }
  acc += b_out[0];
  xs[n] = lrelu01(acc);
}

__global__ __launch_bounds__(128) void k_fc1_init(const float* __restrict__ fc1_b, float* hfc){
  if (threadIdx.x < 128) hfc[threadIdx.x] = fc1_b[threadIdx.x];
}

__global__ __launch_bounds__(256) void k_fc1(const float* __restrict__ xs,
                                             const float* __restrict__ W,
                                             float* hfc){
  int j = threadIdx.x & 127, half = threadIdx.x >> 7;
  float acc = 0.f;
  for (int n = blockIdx.x*2 + half; n < NN; n += gridDim.x*2)
    acc = fmaf(xs[n], W[(size_t)n*128 + j], acc);
  __shared__ float ls[256];
  ls[threadIdx.x] = acc;
  __syncthreads();
  if (threadIdx.x < 128) atomicAdd(&hfc[j], ls[j] + ls[128 + j]);
}

__global__ __launch_bounds__(256) void k_fc2(const float* __restrict__ hfc,
                                             const float* __restrict__ W2,
                                             const float* __restrict__ b2,
                                             float* __restrict__ out){
  __shared__ float hs[128];
  if (threadIdx.x < 128){ float v = hfc[threadIdx.x]; hs[threadIdx.x] = v > 0.f ? v : 0.f; }
  __syncthreads();
  int p = blockIdx.x*256 + threadIdx.x;
  if (p < POI){
    float acc = b2[p];
    #pragma unroll
    for (int j = 0; j < 128; j++) acc = fmaf(hs[j], W2[(size_t)j*POI + p], acc);
    out[p] = acc > 0.f ? acc : 0.f;
  }
}

// ---------------- launch ----------------
extern "C" void kernel_launch(void* const* d_in, const int* in_sizes, int n_in,
                              void* d_out, int out_size, void* d_ws, size_t ws_size,
                              hipStream_t stream) {
  const int*   poi_idx = (const int*)d_in[0];
  const int*   cat_idx = (const int*)d_in[1];
  const float* feat    = (const float*)d_in[2];
  const int*   eidx    = (const int*)d_in[3];
  const int*   src     = eidx;
  const int*   dst     = eidx + NE;
  const float* ew      = (const float*)d_in[4];
  const float* poi_emb = (const float*)d_in[5];
  const float* cat_emb = (const float*)d_in[6];
  const float* W_in    = (const float*)d_in[7];
  const float* b_in    = (const float*)d_in[8];
  const float* gcn_W   = (const float*)d_in[9];
  const float* gcn_b   = (const float*)d_in[10];
  const float* gn_w    = (const float*)d_in[11];
  const float* gn_b    = (const float*)d_in[12];
  const float* gn_a    = (const float*)d_in[13];
  const float* gat_W   = (const float*)d_in[14];
  const float* att_s   = (const float*)d_in[15];
  const float* att_d   = (const float*)d_in[16];
  const float* gat_b   = (const float*)d_in[17];
  const float* W_out   = (const float*)d_in[18];
  const float* b_out   = (const float*)d_in[19];
  const float* fc1_W   = (const float*)d_in[20];
  const float* fc1_b   = (const float*)d_in[21];
  const float* fc2_W   = (const float*)d_in[22];
  const float* fc2_b   = (const float*)d_in[23];
  float* out = (float*)d_out;

  char* p = (char*)d_ws;
  auto alloc = [&](size_t bytes){ void* r = (void*)p; p += (bytes + 255) & ~(size_t)255; return r; };
  float* x      = (float*)alloc((size_t)NN*64*4);
  float* t      = (float*)alloc((size_t)NN*64*4);
  float* h      = (float*)alloc((size_t)POI*64*4);   // also holds poi_proj
  float* cproj  = (float*)alloc((size_t)400*64*4);
  int*   partial= (int*)  alloc((size_t)NWG*NN*4);
  int2*  cw     = (int2*) alloc((size_t)NE*8);
  float* dinv   = (float*)alloc(NN*4);
  int*   counts = (int*)  alloc(NN*4);
  int*   rowptr = (int*)  alloc((NN+1)*4);
  float* a_s    = (float*)alloc(NN*4);
  float* a_d    = (float*)alloc(NN*4);
  float* stats  = (float*)alloc(256*4);
  float* pstats = (float*)alloc(64*128*4);
  float* h1     = (float*)alloc(NN*4);
  float* xs     = (float*)alloc(NN*4);
  float* hfc    = (float*)alloc(256*4);

  const int G_N   = (NN + 255)/256;     // 150
  const int G_W4  = NN/4;               // 9583 (exact)
  const int G_L   = (NN + 31)/32;       // 1199
  const int G_PP  = (POI + 31)/32;      // 1199
  const int G_EL  = NN*64/256;          // 9583 (exact)

  // ---- setup: atomic-free CSR build ----
  k_hist   <<<NWG, 1024, 0, stream>>>(dst, partial);
  k_b1     <<<G_N, 256, 0, stream>>>(partial, counts);
  k_scan   <<<1, 1024, 0, stream>>>(counts, rowptr);
  k_scatter<<<NWG, 1024, 0, stream>>>(src, dst, ew, rowptr, partial, cw);
  k_dinv   <<<G_W4, 256, 0, stream>>>(rowptr, cw, dinv);
  k_scale  <<<G_W4, 256, 0, stream>>>(rowptr, dinv, cw);

  // ---- input layer ----
  k_proj<300><<<G_PP, 256, 0, stream>>>(poi_emb, W_in, h, POI);
  k_proj<100><<<13, 256, 0, stream>>>(cat_emb, W_in + 300*64, cproj, 400);
  k_gather<<<G_EL, 256, 0, stream>>>(poi_idx, cat_idx, feat, h, cproj, W_in + 400*64, t);
  k_gcn_prop<true><<<G_W4, 256, 0, stream>>>(t, rowptr, cw, dinv, b_in, x);

  for (int i = 0; i < 5; i++){
    // GCN branch (resid of previous GAT-graphnorm folded in for i>0)
    if (i == 0)
      k_lin64f<false,false><<<G_L, 256, 0, stream>>>(x, nullptr, nullptr, nullptr,
                                                     gcn_W, nullptr, nullptr, h, nullptr, nullptr);
    else
      k_lin64f<false,true><<<G_L, 256, 0, stream>>>(x, t, stats, gn_b + (i-1)*64,
                                                    gcn_W + i*4096, nullptr, nullptr, h, nullptr, nullptr);
    k_gcn_prop<false><<<G_W4, 256, 0, stream>>>(h, rowptr, cw, dinv, gcn_b + i*64, t);
    k_colstats<<<64, 256, 0, stream>>>(t, pstats);
    k_chan<<<1, 64, 0, stream>>>(pstats, gn_w + i*64, gn_a + i*64, stats);
    // GAT branch (resid of GCN-graphnorm folded in; attention dots fused)
    k_lin64f<true,true><<<G_L, 256, 0, stream>>>(x, t, stats, gn_b + i*64,
                                                 gat_W + i*4096, att_s + i*64, att_d + i*64, h, a_s, a_d);
    k_gat_prop<<<G_W4, 256, 0, stream>>>(h, rowptr, cw, a_s, a_d, gat_b + i*64, t);
    k_colstats<<<64, 256, 0, stream>>>(t, pstats);
    k_chan<<<1, 64, 0, stream>>>(pstats, gn_w + i*64, gn_a + i*64, stats);
  }

  // ---- output head (final resid folded into the dot) ----
  k_outlinf<<<G_W4, 256, 0, stream>>>(x, t, stats, gn_b + 4*64, W_out, h1);
  k_prop1<<<G_N, 256, 0, stream>>>(h1, rowptr, cw, dinv, b_out, xs);
  k_fc1_init<<<1, 128, 0, stream>>>(fc1_b, hfc);
  k_fc1<<<256, 256, 0, stream>>>(xs, fc1_W, hfc);
  k_fc2<<<(POI + 255)/256, 256, 0, stream>>>(hfc, fc2_W, fc2_b, out);
}

// Round 4
// 1304.883 us; speedup vs baseline: 1.8651x; 1.0339x over previous
//
#include <hip/hip_runtime.h>
#include <hip/hip_fp16.h>

#define NN 38332
#define NE 1200000
#define POI 38333
#define NWG 128
#define CHUNK (NE/NWG)   // 9375 exactly

__device__ __forceinline__ float lrelu01(float v){ return v > 0.f ? v : 0.01f*v; }

// ---------------- setup phase A: LDS-privatized histogram ----------------
__global__ __launch_bounds__(1024) void k_hist(const int* __restrict__ dst,
                                               int* __restrict__ partial){
  __shared__ int hist[NN];
  for (int i = threadIdx.x; i < NN; i += 1024) hist[i] = 0;
  __syncthreads();
  int base = blockIdx.x*CHUNK;
  for (int k = threadIdx.x; k < CHUNK; k += 1024)
    atomicAdd(&hist[dst[base + k]], 1);
  __syncthreads();
  for (int i = threadIdx.x; i < NN; i += 1024)
    partial[(size_t)blockIdx.x*NN + i] = hist[i];
}

// ---------------- phase B1: per-bin WG exclusive prefix + total counts ----------------
__global__ __launch_bounds__(256) void k_b1(int* __restrict__ partial, int* __restrict__ counts){
  int bin = blockIdx.x*256 + threadIdx.x;
  if (bin < NN){
    int run = 0;
    for (int wg = 0; wg < NWG; ++wg){
      int v = partial[(size_t)wg*NN + bin];
      partial[(size_t)wg*NN + bin] = run;
      run += v;
    }
    counts[bin] = run;
  }
}

// ---------------- phase B2: rowptr scan (single WG) ----------------
__global__ __launch_bounds__(1024) void k_scan(const int* __restrict__ counts, int* rowptr){
  __shared__ int part[1024];
  int tid = threadIdx.x;
  const int per = (NN + 1023)/1024;   // 38
  int base = tid*per;
  int s = 0;
  for (int k = 0; k < per; k++){ int i = base + k; if (i < NN) s += counts[i]; }
  part[tid] = s;
  __syncthreads();
  for (int off = 1; off < 1024; off <<= 1){
    int v = (tid >= off) ? part[tid-off] : 0;
    __syncthreads();
    part[tid] += v;
    __syncthreads();
  }
  int run = (tid == 0) ? 0 : part[tid-1];
  for (int k = 0; k < per; k++){
    int i = base + k;
    if (i < NN){ rowptr[i] = run; run += counts[i]; }
  }
  if (tid == 1023) rowptr[NN] = run;
}

// ---------------- phase C: scatter with LDS cursors ----------------
__global__ __launch_bounds__(1024) void k_scatter(const int* __restrict__ src,
                                                  const int* __restrict__ dst,
                                                  const float* __restrict__ ew,
                                                  const int* __restrict__ rowptr,
                                                  const int* __restrict__ partial,
                                                  int2* __restrict__ cw){
  __shared__ int cur[NN];
  for (int i = threadIdx.x; i < NN; i += 1024)
    cur[i] = rowptr[i] + partial[(size_t)blockIdx.x*NN + i];
  __syncthreads();
  int base = blockIdx.x*CHUNK;
  for (int k = threadIdx.x; k < CHUNK; k += 1024){
    int e = base + k;
    int d = dst[e];
    int pos = atomicAdd(&cur[d], 1);
    cw[pos] = make_int2(src[e], __float_as_int(ew[e]));
  }
}

// ---------------- phase D: dinv ----------------
__global__ __launch_bounds__(256) void k_dinv(const int* __restrict__ rowptr,
                                              const int2* __restrict__ cw,
                                              float* __restrict__ dinv){
  int lane = threadIdx.x & 63;
  int n = blockIdx.x*4 + (threadIdx.x >> 6);   // NN % 4 == 0
  int beg = rowptr[n], end = rowptr[n+1];
  float s = 0.f;
  for (int e = beg + lane; e < end; e += 64) s += __int_as_float(cw[e].y);
  #pragma unroll
  for (int off = 32; off; off >>= 1) s += __shfl_xor(s, off);
  if (lane == 0) dinv[n] = rsqrtf(1.0f + s);
}

// ---------------- phase E: w -> symmetric norm in place ----------------
__global__ __launch_bounds__(256) void k_scale(const int* __restrict__ rowptr,
                                               const float* __restrict__ dinv,
                                               int2* __restrict__ cw){
  int lane = threadIdx.x & 63;
  int n = blockIdx.x*4 + (threadIdx.x >> 6);
  float dn = dinv[n];
  int beg = rowptr[n], end = rowptr[n+1];
  for (int e = beg + lane; e < end; e += 64){
    int2 p = cw[e];
    cw[e].y = __float_as_int(dinv[p.x]*__int_as_float(p.y)*dn);
  }
}

// ---------------- dense projection ----------------
template<int K>
__global__ __launch_bounds__(256) void k_proj(const float* __restrict__ emb,
                                              const float* __restrict__ W,
                                              float* __restrict__ outp, int rows){
  int lane = threadIdx.x & 63;
  int base = __builtin_amdgcn_readfirstlane(blockIdx.x*32 + (threadIdx.x >> 6)*8);
  float acc[8] = {0.f,0.f,0.f,0.f,0.f,0.f,0.f,0.f};
  constexpr int NCH = (K + 63)/64;
  #pragma unroll
  for (int ch = 0; ch < NCH; ++ch){
    float Wreg[64];
    #pragma unroll
    for (int j = 0; j < 64; ++j)
      Wreg[j] = (ch*64 + j < K) ? W[(ch*64 + j)*64 + lane] : 0.f;
    #pragma unroll
    for (int r = 0; r < 8; ++r){
      int row = base + r;
      if (row < rows){
        const float* er = emb + (size_t)row*K + ch*64;
        #pragma unroll
        for (int j = 0; j < 64; ++j)
          if (ch*64 + j < K) acc[r] = fmaf(er[j], Wreg[j], acc[r]);
      }
    }
  }
  #pragma unroll
  for (int r = 0; r < 8; ++r){
    int row = base + r;
    if (row < rows) outp[(size_t)row*64 + lane] = acc[r];
  }
}

__global__ __launch_bounds__(256) void k_gather(const int* __restrict__ poi_idx,
                                                const int* __restrict__ cat_idx,
                                                const float* __restrict__ feat,
                                                const float* __restrict__ pproj,
                                                const float* __restrict__ cproj,
                                                const float* __restrict__ Wf,
                                                float* __restrict__ outh){
  int i = blockIdx.x*256 + threadIdx.x;   // NN*64 % 256 == 0
  int n = i >> 6, c = i & 63;
  float f0 = feat[n*3], f1 = feat[n*3+1], f2 = feat[n*3+2];
  float v = pproj[(size_t)poi_idx[n]*64 + c] + cproj[(size_t)cat_idx[n]*64 + c];
  v = fmaf(f0, Wf[c], v);
  v = fmaf(f1, Wf[64 + c], v);
  v = fmaf(f2, Wf[128 + c], v);
  outh[i] = v;
}

// ---------------- fused [stats + graphnorm-residual] + 64x64 linear (+ att dots), fp16 h out ----------------
template<bool ATT, bool RESID>
__global__ __launch_bounds__(256) void k_lin64f(float* __restrict__ x,
                                                const float* __restrict__ t,
                                                const float* __restrict__ pstats,
                                                const float* __restrict__ gw,
                                                const float* __restrict__ ga,
                                                const float* __restrict__ gb,
                                                const float* __restrict__ W,
                                                const float* __restrict__ att_src,
                                                const float* __restrict__ att_dst,
                                                __half* __restrict__ h,
                                                float* __restrict__ a_s,
                                                float* __restrict__ a_d){
  int lane = threadIdx.x & 63;
  int base = blockIdx.x*32 + (threadIdx.x >> 6)*8;
  float Wreg[64];
  #pragma unroll
  for (int j = 0; j < 64; ++j) Wreg[j] = W[j*64 + lane];
  float coef = 0.f, shift = 0.f, gbv = 0.f;
  if (RESID){
    float s = 0.f, s2 = 0.f;
    for (int blk = 0; blk < 64; ++blk){
      s  += pstats[blk*128 + lane];
      s2 += pstats[blk*128 + 64 + lane];
    }
    const float invN = 1.0f/(float)NN;
    float m  = s*invN, ms = s2*invN, a = ga[lane];
    float var = ms - m*m*a*(2.0f - a);
    coef  = rsqrtf(var + 1e-5f)*gw[lane];
    shift = a*m;
    gbv   = gb[lane];
  }
  float as_l = 0.f, ad_l = 0.f;
  if (ATT){ as_l = att_src[lane]; ad_l = att_dst[lane]; }
  #pragma unroll
  for (int r = 0; r < 8; ++r){
    int row = base + r;
    if (row < NN){
      float xn = x[(size_t)row*64 + lane];
      if (RESID){
        float tv = t[(size_t)row*64 + lane];
        xn += lrelu01((tv - shift)*coef + gbv);
        x[(size_t)row*64 + lane] = xn;
      }
      int xi = __float_as_int(xn);
      float acc = 0.f;
      #pragma unroll
      for (int j = 0; j < 64; ++j)
        acc = fmaf(__int_as_float(__builtin_amdgcn_readlane(xi, j)), Wreg[j], acc);
      h[(size_t)row*64 + lane] = __float2half(acc);
      if (ATT){
        float s1 = acc*as_l, s2 = acc*ad_l;
        #pragma unroll
        for (int off = 32; off; off >>= 1){ s1 += __shfl_xor(s1, off); s2 += __shfl_xor(s2, off); }
        if (lane == 0){ a_s[row] = s1; a_d[row] = s2; }
      }
    }
  }
}

// ---------------- GCN propagation, templated gather type ----------------
template<bool DO_LRELU, typename T>
__global__ __launch_bounds__(256) void k_gcn_prop(const T* __restrict__ h,
                                                  const int* __restrict__ rowptr,
                                                  const int2* __restrict__ cw,
                                                  const float* __restrict__ dinv,
                                                  const float* __restrict__ b,
                                                  float* __restrict__ out){
  int lane = threadIdx.x & 63;
  int n = __builtin_amdgcn_readfirstlane(blockIdx.x*4 + (threadIdx.x >> 6));
  int beg = rowptr[n], end = rowptr[n+1];
  float di = dinv[n];
  float a0 = di*di*(float)h[(size_t)n*64 + lane];
  float a1=0.f,a2=0.f,a3=0.f,a4=0.f,a5=0.f,a6=0.f,a7=0.f;
  int e = beg;
  for (; e + 8 <= end; e += 8){
    int2 p0=cw[e],p1=cw[e+1],p2=cw[e+2],p3=cw[e+3],p4=cw[e+4],p5=cw[e+5],p6=cw[e+6],p7=cw[e+7];
    a0 = fmaf(__int_as_float(p0.y), (float)h[(size_t)p0.x*64 + lane], a0);
    a1 = fmaf(__int_as_float(p1.y), (float)h[(size_t)p1.x*64 + lane], a1);
    a2 = fmaf(__int_as_float(p2.y), (float)h[(size_t)p2.x*64 + lane], a2);
    a3 = fmaf(__int_as_float(p3.y), (float)h[(size_t)p3.x*64 + lane], a3);
    a4 = fmaf(__int_as_float(p4.y), (float)h[(size_t)p4.x*64 + lane], a4);
    a5 = fmaf(__int_as_float(p5.y), (float)h[(size_t)p5.x*64 + lane], a5);
    a6 = fmaf(__int_as_float(p6.y), (float)h[(size_t)p6.x*64 + lane], a6);
    a7 = fmaf(__int_as_float(p7.y), (float)h[(size_t)p7.x*64 + lane], a7);
  }
  for (; e < end; ++e){
    int2 p = cw[e];
    a0 = fmaf(__int_as_float(p.y), (float)h[(size_t)p.x*64 + lane], a0);
  }
  float acc = ((a0+a1)+(a2+a3)) + ((a4+a5)+(a6+a7)) + b[lane];
  if (DO_LRELU) acc = lrelu01(acc);
  out[(size_t)n*64 + lane] = acc;
}

// ---------------- GAT propagation (fp16 h) ----------------
__global__ __launch_bounds__(256) void k_gat_prop(const __half* __restrict__ h,
                                                  const int* __restrict__ rowptr,
                                                  const int2* __restrict__ cw,
                                                  const float* __restrict__ a_s,
                                                  const float* __restrict__ a_d,
                                                  const float* __restrict__ b,
                                                  float* __restrict__ out){
  int lane = threadIdx.x & 63;
  int n = __builtin_amdgcn_readfirstlane(blockIdx.x*4 + (threadIdx.x >> 6));
  int beg = rowptr[n], end = rowptr[n+1];
  int deg = end - beg;
  float ad = a_d[n];
  float se = a_s[n] + ad; se = se > 0.f ? se : 0.2f*se;
  float acc, zinv;
  if (deg <= 64){
    int s = 0; float v = -1e30f;
    if (lane < deg){
      s = cw[beg + lane].x;
      v = a_s[s] + ad; v = v > 0.f ? v : 0.2f*v;
    }
    float m = fmaxf(se, v);
    #pragma unroll
    for (int off = 32; off; off >>= 1) m = fmaxf(m, __shfl_xor(m, off));
    float ev = (lane < deg) ? __expf(v - m) : 0.f;
    float z = ev;
    #pragma unroll
    for (int off = 32; off; off >>= 1) z += __shfl_xor(z, off);
    float es = __expf(se - m);
    z += es;
    zinv = 1.0f/(z + 1e-16f);
    acc = es*(float)h[(size_t)n*64 + lane];
    float acc2 = 0.f;
    int j = 0;
    for (; j + 2 <= deg; j += 2){
      float w0 = __shfl(ev, j),   w1 = __shfl(ev, j+1);
      int   s0 = __shfl(s,  j),   s1 = __shfl(s,  j+1);
      acc  = fmaf(w0, (float)h[(size_t)s0*64 + lane], acc);
      acc2 = fmaf(w1, (float)h[(size_t)s1*64 + lane], acc2);
    }
    if (j < deg){
      float w0 = __shfl(ev, j); int s0 = __shfl(s, j);
      acc = fmaf(w0, (float)h[(size_t)s0*64 + lane], acc);
    }
    acc += acc2;
  } else {
    float m = se;
    for (int e = beg + lane; e < end; e += 64){
      float v = a_s[cw[e].x] + ad; v = v > 0.f ? v : 0.2f*v;
      m = fmaxf(m, v);
    }
    #pragma unroll
    for (int off = 32; off; off >>= 1) m = fmaxf(m, __shfl_xor(m, off));
    float z = 0.f;
    for (int e = beg + lane; e < end; e += 64){
      float v = a_s[cw[e].x] + ad; v = v > 0.f ? v : 0.2f*v;
      z += __expf(v - m);
    }
    #pragma unroll
    for (int off = 32; off; off >>= 1) z += __shfl_xor(z, off);
    float es = __expf(se - m);
    z += es;
    zinv = 1.0f/(z + 1e-16f);
    acc = es*(float)h[(size_t)n*64 + lane];
    for (int e = beg; e < end; ++e){
      int sj = cw[e].x;
      float v = a_s[sj] + ad; v = v > 0.f ? v : 0.2f*v;
      acc = fmaf(__expf(v - m), (float)h[(size_t)sj*64 + lane], acc);
    }
  }
  out[(size_t)n*64 + lane] = acc*zinv + b[lane];
}

// ---------------- GraphNorm stats: per-block partials ----------------
__global__ __launch_bounds__(256) void k_colstats(const float* __restrict__ t,
                                                  float* __restrict__ pstats){
  int lane = threadIdx.x & 63;
  int sub  = threadIdx.x >> 6;
  float s = 0.f, s2 = 0.f;
  for (int n = blockIdx.x*4 + sub; n < NN; n += gridDim.x*4){
    float v = t[(size_t)n*64 + lane];
    s += v; s2 = fmaf(v, v, s2);
  }
  __shared__ float ls[256], ls2[256];
  ls[threadIdx.x] = s; ls2[threadIdx.x] = s2;
  __syncthreads();
  if (threadIdx.x < 64){
    s  = ls[threadIdx.x]  + ls[threadIdx.x+64]  + ls[threadIdx.x+128]  + ls[threadIdx.x+192];
    s2 = ls2[threadIdx.x] + ls2[threadIdx.x+64] + ls2[threadIdx.x+128] + ls2[threadIdx.x+192];
    pstats[blockIdx.x*128 + threadIdx.x]      = s;
    pstats[blockIdx.x*128 + 64 + threadIdx.x] = s2;
  }
}

// ---------------- output head: fused stats + resid + dot ----------------
__global__ __launch_bounds__(256) void k_outlinf(const float* __restrict__ x,
                                                 const float* __restrict__ t,
                                                 const float* __restrict__ pstats,
                                                 const float* __restrict__ gw,
                                                 const float* __restrict__ ga,
                                                 const float* __restrict__ gb,
                                                 const float* __restrict__ Wout,
                                                 float* __restrict__ h1){
  int lane = threadIdx.x & 63, wave = threadIdx.x >> 6;
  int n = blockIdx.x*4 + wave;
  float s = 0.f, s2 = 0.f;
  for (int blk = 0; blk < 64; ++blk){
    s  += pstats[blk*128 + lane];
    s2 += pstats[blk*128 + 64 + lane];
  }
  const float invN = 1.0f/(float)NN;
  float m  = s*invN, ms = s2*invN, a = ga[lane];
  float var = ms - m*m*a*(2.0f - a);
  float coef  = rsqrtf(var + 1e-5f)*gw[lane];
  float shift = a*m;
  float xn = x[(size_t)n*64 + lane];
  float tv = t[(size_t)n*64 + lane];
  xn += lrelu01((tv - shift)*coef + gb[lane]);
  float v = xn*Wout[lane];
  #pragma unroll
  for (int off = 32; off; off >>= 1) v += __shfl_xor(v, off);
  if (lane == 0) h1[n] = v;
}

__global__ __launch_bounds__(256) void k_prop1(const float* __restrict__ h1,
                                               const int* __restrict__ rowptr,
                                               const int2* __restrict__ cw,
                                               const float* __restrict__ dinv,
                                               const float* __restrict__ b_out,
                                               float* __restrict__ xs){
  int n = blockIdx.x*256 + threadIdx.x;
  if (n >= NN) return;
  float di = dinv[n];
  float acc = di*di*h1[n];
  int beg = rowptr[n], end = rowptr[n+1];
  for (int e = beg; e < end; e++){
    int2 p = cw[e];
    acc = fmaf(__int_as_float(p.y), h1[p.x], acc);
  }
  acc += b_out[0];
  xs[n] = lrelu01(acc);
}

// ---------------- FC head: partials, no atomics ----------------
__global__ __launch_bounds__(256) void k_fc1(const float* __restrict__ xs,
                                             const float* __restrict__ W,
                                             float* __restrict__ pfc){
  int j = threadIdx.x & 127, half = threadIdx.x >> 7;
  float acc = 0.f;
  for (int n = blockIdx.x*2 + half; n < NN; n += gridDim.x*2)
    acc = fmaf(xs[n], W[(size_t)n*128 + j], acc);
  __shared__ float ls[256];
  ls[threadIdx.x] = acc;
  __syncthreads();
  if (threadIdx.x < 128) pfc[blockIdx.x*128 + j] = ls[j] + ls[128 + j];
}

__global__ __launch_bounds__(256) void k_fc2(const float* __restrict__ pfc,
                                             const float* __restrict__ fc1_b,
                                             const float* __restrict__ W2,
                                             const float* __restrict__ b2,
                                             float* __restrict__ out){
  __shared__ float hs[128];
  if (threadIdx.x < 128){
    float v = fc1_b[threadIdx.x];
    for (int blk = 0; blk < 128; ++blk) v += pfc[blk*128 + threadIdx.x];
    hs[threadIdx.x] = v > 0.f ? v : 0.f;
  }
  __syncthreads();
  int p = blockIdx.x*256 + threadIdx.x;
  if (p < POI){
    float acc = b2[p];
    #pragma unroll
    for (int j = 0; j < 128; j++) acc = fmaf(hs[j], W2[(size_t)j*POI + p], acc);
    out[p] = acc > 0.f ? acc : 0.f;
  }
}

// ---------------- launch ----------------
extern "C" void kernel_launch(void* const* d_in, const int* in_sizes, int n_in,
                              void* d_out, int out_size, void* d_ws, size_t ws_size,
                              hipStream_t stream) {
  const int*   poi_idx = (const int*)d_in[0];
  const int*   cat_idx = (const int*)d_in[1];
  const float* feat    = (const float*)d_in[2];
  const int*   eidx    = (const int*)d_in[3];
  const int*   src     = eidx;
  const int*   dst     = eidx + NE;
  const float* ew      = (const float*)d_in[4];
  const float* poi_emb = (const float*)d_in[5];
  const float* cat_emb = (const float*)d_in[6];
  const float* W_in    = (const float*)d_in[7];
  const float* b_in    = (const float*)d_in[8];
  const float* gcn_W   = (const float*)d_in[9];
  const float* gcn_b   = (const float*)d_in[10];
  const float* gn_w    = (const float*)d_in[11];
  const float* gn_b    = (const float*)d_in[12];
  const float* gn_a    = (const float*)d_in[13];
  const float* gat_W   = (const float*)d_in[14];
  const float* att_s   = (const float*)d_in[15];
  const float* att_d   = (const float*)d_in[16];
  const float* gat_b   = (const float*)d_in[17];
  const float* W_out   = (const float*)d_in[18];
  const float* b_out   = (const float*)d_in[19];
  const float* fc1_W   = (const float*)d_in[20];
  const float* fc1_b   = (const float*)d_in[21];
  const float* fc2_W   = (const float*)d_in[22];
  const float* fc2_b   = (const float*)d_in[23];
  float* out = (float*)d_out;

  char* p = (char*)d_ws;
  auto alloc = [&](size_t bytes){ void* r = (void*)p; p += (bytes + 255) & ~(size_t)255; return r; };
  float*  x      = (float*) alloc((size_t)NN*64*4);
  float*  t      = (float*) alloc((size_t)NN*64*4);
  __half* h      = (__half*)alloc((size_t)NN*64*2);
  int*    partial= (int*)   alloc((size_t)NWG*NN*4);   // 19.6 MB; aliased by pproj after setup
  float*  pproj  = (float*) partial;                   // POI*64*4 = 9.8 MB fits
  float*  cproj  = (float*) alloc((size_t)400*64*4);
  int2*   cw     = (int2*)  alloc((size_t)NE*8);
  float*  dinv   = (float*) alloc(NN*4);
  int*    counts = (int*)   alloc(NN*4);
  int*    rowptr = (int*)   alloc((NN+1)*4);
  float*  a_s    = (float*) alloc(NN*4);
  float*  a_d    = (float*) alloc(NN*4);
  float*  pstats = (float*) alloc(64*128*4);
  float*  h1     = (float*) alloc(NN*4);
  float*  xs     = (float*) alloc(NN*4);
  float*  pfc    = (float*) alloc(128*128*4);

  const int G_N   = (NN + 255)/256;     // 150
  const int G_W4  = NN/4;               // 9583 (exact)
  const int G_L   = (NN + 31)/32;       // 1199
  const int G_PP  = (POI + 31)/32;      // 1199
  const int G_EL  = NN*64/256;          // 9583 (exact)

  // ---- setup: CSR build (LDS-privatized, 128 WGs) ----
  k_hist   <<<NWG, 1024, 0, stream>>>(dst, partial);
  k_b1     <<<G_N, 256, 0, stream>>>(partial, counts);
  k_scan   <<<1, 1024, 0, stream>>>(counts, rowptr);
  k_scatter<<<NWG, 1024, 0, stream>>>(src, dst, ew, rowptr, partial, cw);
  k_dinv   <<<G_W4, 256, 0, stream>>>(rowptr, cw, dinv);
  k_scale  <<<G_W4, 256, 0, stream>>>(rowptr, dinv, cw);

  // ---- input layer (fp32 path) ----
  k_proj<300><<<G_PP, 256, 0, stream>>>(poi_emb, W_in, pproj, POI);
  k_proj<100><<<13, 256, 0, stream>>>(cat_emb, W_in + 300*64, cproj, 400);
  k_gather<<<G_EL, 256, 0, stream>>>(poi_idx, cat_idx, feat, pproj, cproj, W_in + 400*64, t);
  k_gcn_prop<true, float><<<G_W4, 256, 0, stream>>>(t, rowptr, cw, dinv, b_in, x);

  for (int i = 0; i < 5; i++){
    // GCN branch (previous GAT graphnorm-resid folded in for i>0)
    if (i == 0)
      k_lin64f<false,false><<<G_L, 256, 0, stream>>>(x, nullptr, nullptr, nullptr, nullptr, nullptr,
                                                     gcn_W, nullptr, nullptr, h, nullptr, nullptr);
    else
      k_lin64f<false,true><<<G_L, 256, 0, stream>>>(x, t, pstats, gn_w + (i-1)*64, gn_a + (i-1)*64, gn_b + (i-1)*64,
                                                    gcn_W + i*4096, nullptr, nullptr, h, nullptr, nullptr);
    k_gcn_prop<false, __half><<<G_W4, 256, 0, stream>>>(h, rowptr, cw, dinv, gcn_b + i*64, t);
    k_colstats<<<64, 256, 0, stream>>>(t, pstats);
    // GAT branch (GCN graphnorm-resid folded in; attention dots fused)
    k_lin64f<true,true><<<G_L, 256, 0, stream>>>(x, t, pstats, gn_w + i*64, gn_a + i*64, gn_b + i*64,
                                                 gat_W + i*4096, att_s + i*64, att_d + i*64, h, a_s, a_d);
    k_gat_prop<<<G_W4, 256, 0, stream>>>(h, rowptr, cw, a_s, a_d, gat_b + i*64, t);
    k_colstats<<<64, 256, 0, stream>>>(t, pstats);
  }

  // ---- output head (final resid + stats folded into the dot) ----
  k_outlinf<<<G_W4, 256, 0, stream>>>(x, t, pstats, gn_w + 4*64, gn_a + 4*64, gn_b + 4*64, W_out, h1);
  k_prop1<<<G_N, 256, 0, stream>>>(h1, rowptr, cw, dinv, b_out, xs);
  k_fc1<<<128, 256, 0, stream>>>(xs, fc1_W, pfc);
  k_fc2<<<(POI + 255)/256, 256, 0, stream>>>(pfc, fc1_b, fc2_W, fc2_b, out);
}